// Round 18
// baseline (110.558 us; speedup 1.0000x reference)
//
#include <hip/hip_runtime.h>

#define NTOK 2304   // 48*48 tokens
#define NH 12
#define HD 64

typedef __attribute__((ext_vector_type(8))) short bf16x8;
typedef __attribute__((ext_vector_type(4))) float f32x4;

__device__ __forceinline__ unsigned short f2bf(float f){
  union { float f; unsigned u; } v; v.f = f;
  unsigned r = v.u + 0x7fffu + ((v.u >> 16) & 1u);
  return (unsigned short)(r >> 16);
}
__device__ __forceinline__ float bf2f(unsigned short h){
  union { unsigned u; float f; } v; v.u = ((unsigned)h) << 16;
  return v.f;
}
__device__ __forceinline__ float fast_exp2(float x){
  float r;
  asm("v_exp_f32 %0, %1" : "=v"(r) : "v"(x));   // D = 2^S0, single trans op
  return r;
}
__device__ __forceinline__ void gload_lds16(const void* g, void* lds){
  __builtin_amdgcn_global_load_lds(
    (const __attribute__((address_space(1))) unsigned int*)g,
    (__attribute__((address_space(3))) unsigned int*)lds, 16, 0, 0);
}

// ---------------- fp32 -> bf16 convert (x, qkv_w, proj_w) ----------------
__global__ __launch_bounds__(256) void cvt_all(
    const float* __restrict__ x, const float* __restrict__ qw, const float* __restrict__ pw,
    unsigned short* __restrict__ xb, unsigned short* __restrict__ wqb, unsigned short* __restrict__ wpb){
  int i = blockIdx.x * 256 + threadIdx.x;   // 1032192 float4 units total
  const float* src; unsigned short* dst; int off;
  if (i < 442368)      { src = x;  dst = xb;  off = i; }
  else if (i < 884736) { src = qw; dst = wqb; off = i - 442368; }
  else                 { src = pw; dst = wpb; off = i - 884736; }
  float4 v = ((const float4*)src)[off];
  union { unsigned short u[4]; unsigned long long ll; } o;
  o.u[0] = f2bf(v.x); o.u[1] = f2bf(v.y); o.u[2] = f2bf(v.z); o.u[3] = f2bf(v.w);
  ((unsigned long long*)dst)[off] = o.ll;
}

// ---------------- LoRA t = x @ A^T  (t[3][2304][4]) ----------------
__global__ __launch_bounds__(256) void lora_t_kernel(const float* __restrict__ x,
    const float* __restrict__ Aq, const float* __restrict__ Ak, const float* __restrict__ Av,
    float* __restrict__ t){
  int wave = (blockIdx.x * 256 + threadIdx.x) >> 6;   // token
  int lane = threadIdx.x & 63;
  if (wave >= NTOK) return;
  const float* xr = x + (size_t)wave * 768;
  float part[12];
  #pragma unroll
  for (int j = 0; j < 12; j++) part[j] = 0.f;
  for (int k = lane; k < 768; k += 64){
    float xv = xr[k];
    #pragma unroll
    for (int r = 0; r < 4; r++){
      part[r]     += xv * Aq[r*768 + k];
      part[4 + r] += xv * Ak[r*768 + k];
      part[8 + r] += xv * Av[r*768 + k];
    }
  }
  #pragma unroll
  for (int j = 0; j < 12; j++){
    float v = part[j];
    #pragma unroll
    for (int off = 32; off; off >>= 1) v += __shfl_xor(v, off);
    if (lane == 0){
      int mat = j >> 2, r = j & 3;
      t[((size_t)mat * NTOK + wave) * 4 + r] = v;
    }
  }
}

// ---------------- fused qkv GEMM (+bias +LoRA, writes q(scaled),k,vT) ----------------
// q pre-scale = 0.125*log2(e): MFMA emits S*log2e; rel_gemm's G*8 then emits
// rel*log2e automatically -> attn uses raw v_exp_f32 (2^x) with no multiplies.
__global__ __launch_bounds__(256) void qkv_gemm(
    const unsigned short* __restrict__ xg,   // [2304][768] bf16
    const unsigned short* __restrict__ wg,   // [2304][768] bf16
    const float* __restrict__ bias,          // [2304]
    const float* __restrict__ t,             // [3][2304][4]
    const float* __restrict__ Bq, const float* __restrict__ Bk, const float* __restrict__ Bv, // [768][4]
    unsigned short* __restrict__ qo,         // [12][2304][64]  (pre-scaled)
    unsigned short* __restrict__ ko,         // [12][2304][64]
    unsigned short* __restrict__ vT)         // [12][64][2304]
{
  __shared__ short As[128*64];
  __shared__ short Bs[64*64];
  const int tid = threadIdx.x;
  const int lane = tid & 63;
  const int wv = tid >> 6;
  const int r = lane & 15, g = lane >> 4;
  const int wm = (wv >> 1) * 64, wn = (wv & 1) * 32;
  const int m0 = blockIdx.y * 128, n0 = blockIdx.x * 64;

  f32x4 acc[4][2];
  #pragma unroll
  for (int i = 0; i < 4; i++)
    #pragma unroll
    for (int j = 0; j < 2; j++) acc[i][j] = (f32x4){0.f, 0.f, 0.f, 0.f};

  for (int k0 = 0; k0 < 768; k0 += 64){
    __syncthreads();
    #pragma unroll
    for (int it = 0; it < 4; it++){
      int f = it * 256 + tid;
      int row = f >> 3, u = f & 7;
      int us = ((u ^ (row & 7)) << 3);
      gload_lds16(xg + (size_t)(m0 + row) * 768 + k0 + us, &As[f * 8]);
    }
    #pragma unroll
    for (int it = 0; it < 2; it++){
      int f = it * 256 + tid;
      int row = f >> 3, u = f & 7;
      int us = ((u ^ (row & 7)) << 3);
      gload_lds16(wg + (size_t)(n0 + row) * 768 + k0 + us, &Bs[f * 8]);
    }
    __syncthreads();
    #pragma unroll
    for (int ks = 0; ks < 2; ks++){
      bf16x8 af[4], bfr[2];
      #pragma unroll
      for (int mt = 0; mt < 4; mt++){
        int row = wm + mt * 16 + r;
        af[mt] = *(const bf16x8*)&As[row * 64 + ((((ks << 2) | g) ^ (r & 7)) << 3)];
      }
      #pragma unroll
      for (int nt = 0; nt < 2; nt++){
        int row = wn + nt * 16 + r;
        bfr[nt] = *(const bf16x8*)&Bs[row * 64 + ((((ks << 2) | g) ^ (r & 7)) << 3)];
      }
      #pragma unroll
      for (int mt = 0; mt < 4; mt++)
        #pragma unroll
        for (int nt = 0; nt < 2; nt++)
          acc[mt][nt] = __builtin_amdgcn_mfma_f32_16x16x32_bf16(af[mt], bfr[nt], acc[mt][nt], 0, 0, 0);
    }
  }

  const int part = n0 / 768;   // 64 | 768 -> block never straddles parts
  const float* Bl = (part == 0) ? Bq : ((part == 1) ? Bk : Bv);
  const float* tp = t + (size_t)part * NTOK * 4;
  #pragma unroll
  for (int mt = 0; mt < 4; mt++){
    #pragma unroll
    for (int reg = 0; reg < 4; reg++){
      int row_m = m0 + wm + mt * 16 + g * 4 + reg;
      float4 tv = *(const float4*)&tp[row_m * 4];
      #pragma unroll
      for (int nt = 0; nt < 2; nt++){
        int col = n0 + wn + nt * 16 + r;
        int cc = col - part * 768;
        float4 bw = *(const float4*)&Bl[cc * 4];
        float val = acc[mt][nt][reg] + bias[col]
                  + 0.25f * (tv.x * bw.x + tv.y * bw.y + tv.z * bw.z + tv.w * bw.w);
        int head = cc >> 6, d = cc & 63;
        if (part == 0)      qo[((size_t)head * NTOK + row_m) * 64 + d] = f2bf(val * 0.18033688f);
        else if (part == 1) ko[((size_t)head * NTOK + row_m) * 64 + d] = f2bf(val);
        else                vT[((size_t)head * 64 + d) * NTOK + row_m] = f2bf(val);
      }
    }
  }
}

// ---------------- rel_h / rel_w via MFMA (rel_pos converted in-kernel) ----------------
// q carries 0.125*log2e; G*8 therefore yields rel*log2e (what v_exp_f32 needs).
__global__ __launch_bounds__(256, 2) void rel_gemm(
    const unsigned short* __restrict__ qg,    // [12][2304][64] bf16 (scaled)
    const float* __restrict__ rph,            // [95][64] f32
    const float* __restrict__ rpw,            // [95][64] f32
    float* __restrict__ rel_h,                // [12][2304][48]
    float* __restrict__ rel_w)                // [12][2304][48]
{
  __shared__ float G[48 * 196];
  const int ih = blockIdx.x, head = blockIdx.y;
  const int tid = threadIdx.x, lane = tid & 63, wv = tid >> 6;
  const int r = lane & 15, g = lane >> 4;
  const int q0 = ih * 48;

  bf16x8 af[3][2];
  #pragma unroll
  for (int mt = 0; mt < 3; mt++)
    #pragma unroll
    for (int ks = 0; ks < 2; ks++)
      af[mt][ks] = *(const bf16x8*)&qg[((size_t)head * NTOK + q0 + mt * 16 + r) * 64 + ks * 32 + g * 8];

  bf16x8 bfv[3][2];
  #pragma unroll
  for (int nt = 0; nt < 3; nt++){
    int col = wv * 48 + nt * 16 + r;
    const float* src = (col < 95) ? &rph[(size_t)col * 64]
                     : (col < 190) ? &rpw[(size_t)(col - 95) * 64]
                     : &rpw[0];
    #pragma unroll
    for (int ks = 0; ks < 2; ks++){
      float4 lo = *(const float4*)&src[ks * 32 + g * 8];
      float4 hi = *(const float4*)&src[ks * 32 + g * 8 + 4];
      union { unsigned short u[8]; bf16x8 v; } t;
      t.u[0] = f2bf(lo.x); t.u[1] = f2bf(lo.y); t.u[2] = f2bf(lo.z); t.u[3] = f2bf(lo.w);
      t.u[4] = f2bf(hi.x); t.u[5] = f2bf(hi.y); t.u[6] = f2bf(hi.z); t.u[7] = f2bf(hi.w);
      bfv[nt][ks] = t.v;
    }
  }

  f32x4 acc[3][3];
  #pragma unroll
  for (int mt = 0; mt < 3; mt++)
    #pragma unroll
    for (int nt = 0; nt < 3; nt++) acc[mt][nt] = (f32x4){0.f, 0.f, 0.f, 0.f};
  #pragma unroll
  for (int ks = 0; ks < 2; ks++)
    #pragma unroll
    for (int mt = 0; mt < 3; mt++)
      #pragma unroll
      for (int nt = 0; nt < 3; nt++)
        acc[mt][nt] = __builtin_amdgcn_mfma_f32_16x16x32_bf16(af[mt][ks], bfv[nt][ks], acc[mt][nt], 0, 0, 0);

  #pragma unroll
  for (int mt = 0; mt < 3; mt++)
    #pragma unroll
    for (int reg = 0; reg < 4; reg++){
      int row = mt * 16 + g * 4 + reg;
      #pragma unroll
      for (int nt = 0; nt < 3; nt++)
        G[row * 196 + wv * 48 + nt * 16 + r] = acc[mt][nt][reg];
    }
  __syncthreads();

  for (int idx = tid; idx < 48 * 96; idx += 256){
    int i = idx / 96, c = idx % 96;
    size_t gi = (size_t)head * NTOK + q0 + i;
    if (c < 48) rel_h[gi * 48 + c]        = G[i * 196 + (ih + 47 - c)] * 8.f;
    else        rel_w[gi * 48 + (c - 48)] = G[i * 196 + 95 + (i + 47 - (c - 48))] * 8.f;
  }
}

// ---------------- flash attention v15: 128-key tiles, 18 iterations ----------------
// key = 128t + 16ntl + 4g+reg, ntl in [0,8). t = 3a+tb; e = 8tb+ntl:
// kh = 8a + e/3 (lane-uniform, never straddles), kw = 16*(e%3) + 4g+reg.
// K tile [128][64] (same swizzle, 16 segs); V tile [64][128] (16-unit rows,
// XOR touches low-3 bits only on both sides). Redistribution: ks in [0,4),
// W indexed 2ks+hi. LDS 79.1 KB -> 2 blocks/CU. exp via raw v_exp_f32.
__global__ __launch_bounds__(256, 2) void attn_kernel(
    const unsigned short* __restrict__ qg,   // [12][2304][64] scaled (log2e absorbed)
    const unsigned short* __restrict__ kg,   // [12][2304][64]
    const unsigned short* __restrict__ vT,   // [12][64][2304]
    const float* __restrict__ rel_h,         // [12][2304][48] (*log2e)
    const float* __restrict__ rel_w,         // [12][2304][48] (*log2e)
    unsigned short* __restrict__ ao)         // [2304][768]
{
  // Ks[2][128][64]us @0 (32768) | Vs[2][64][128]us @32768 (32768)
  // relH[64][52]f32 @65536 (13312) | lsh @78848 (256)  total 79104
  __shared__ __align__(16) char smem[79104];
  unsigned short* Ks = (unsigned short*)smem;
  unsigned short* Vs = (unsigned short*)(smem + 32768);
  float* relH = (float*)(smem + 65536);
  float* lsh = (float*)(smem + 78848);

  const int head = blockIdx.y;
  const int q0 = blockIdx.x * 64;
  const int tid = threadIdx.x, lane = tid & 63, wv = tid >> 6;
  const int r = lane & 15, g = lane >> 4;

  const unsigned short* kbase = kg + (size_t)head * NTOK * 64;
  const unsigned short* vbase = vT + (size_t)head * 64 * NTOK;

  // rel_h stage (f32, stride 52 -> 16B-aligned rows, float4)
  for (int idx = tid; idx < 64 * 12; idx += 256){
    int i = idx / 12, c4 = idx % 12;
    *(float4*)&relH[i * 52 + c4 * 4] =
        *(const float4*)&rel_h[((size_t)head * NTOK + q0 + i) * 48 + c4 * 4];
  }

  // rel_w: 3 static float4s per lane (row = wv*16+r, cols 16j+4g..+3), full f32
  float4 wreg[3];
  #pragma unroll
  for (int j = 0; j < 3; j++)
    wreg[j] = *(const float4*)&rel_w[((size_t)head * NTOK + q0 + wv * 16 + r) * 48 + j * 16 + g * 4];

  bf16x8 qf[2];
  #pragma unroll
  for (int ks = 0; ks < 2; ks++)
    qf[ks] = *(const bf16x8*)&qg[((size_t)head * NTOK + q0 + wv * 16 + r) * 64 + ks * 32 + g * 8];

  const int rowIn  = lane >> 3, uu  = lane & 7;    // K staging: 8 rows x 8 units
  const int rowIn4 = lane >> 4, u16 = lane & 15;   // V staging: 4 rows x 16 units

#define STAGE_TILE(T, BUFP) do { \
    const int key0_ = (T) * 128; \
    unsigned short* KsX = &Ks[(BUFP) * 8192]; \
    unsigned short* VsX = &Vs[(BUFP) * 8192]; \
    _Pragma("unroll") \
    for (int s2 = 0; s2 < 4; s2++){ \
      int segk = wv * 4 + s2; \
      int rowk = segk * 8 + rowIn; \
      gload_lds16(kbase + (size_t)(key0_ + rowk) * 64 + ((uu ^ (rowk & 7)) << 3), \
                  &KsX[segk * 512 + lane * 8]); \
      int segv = wv * 4 + s2; \
      int rowv = segv * 4 + rowIn4; \
      gload_lds16(vbase + (size_t)rowv * NTOK + key0_ + ((u16 ^ (rowv & 7)) << 3), \
                  &VsX[segv * 512 + lane * 8]); \
    } \
  } while(0)

  // prologue: stage tile 0 into buf 0
  STAGE_TILE(0, 0);
  __syncthreads();

  f32x4 Oa[4];
  float lrun = 0.f;
  #pragma unroll
  for (int dt = 0; dt < 4; dt++) Oa[dt] = (f32x4){0.f, 0.f, 0.f, 0.f};

  const float* rsh = &relH[(wv * 16 + r) * 52];

  // e = 8tb + ntl -> kh = 8a + KH8[tb][ntl], j = J8[tb][ntl]
  const int KH8[3][8] = {{0,0,0,1,1,1,2,2},{2,3,3,3,4,4,4,5},{5,5,6,6,6,7,7,7}};
  const int J8[3][8]  = {{0,1,2,0,1,2,0,1},{2,0,1,2,0,1,2,0},{1,2,0,1,2,0,1,2}};

  const int srcA = r + ((g & 1) << 5);   // lane (r, 2*(g&1))
  const int srcB = srcA + 16;            // lane (r, 2*(g&1)+1)
  const int hi = (g >> 1);

  int buf = 0;
  for (int a = 0; a < 6; a++){
    #pragma unroll
    for (int tb = 0; tb < 3; tb++){
      const int t = a * 3 + tb;
      unsigned short* KsB = &Ks[buf * 8192];
      unsigned short* VsB = &Vs[buf * 8192];

      if (t < 17) STAGE_TILE(t + 1, buf ^ 1);

      // ---- QK^T (swapped): s[ntl] = S[key=16ntl+4g+reg][q=r] ----
      f32x4 s[8];
      __builtin_amdgcn_s_setprio(1);
      #pragma unroll
      for (int ntl = 0; ntl < 8; ntl++){
        bf16x8 kc0 = *(const bf16x8*)&KsB[(ntl * 16 + r) * 64 + ((g ^ (r & 7)) << 3)];
        bf16x8 kc1 = *(const bf16x8*)&KsB[(ntl * 16 + r) * 64 + (((4 + g) ^ (r & 7)) << 3)];
        s[ntl] = (f32x4){0.f, 0.f, 0.f, 0.f};
        s[ntl] = __builtin_amdgcn_mfma_f32_16x16x32_bf16(kc0, qf[0], s[ntl], 0, 0, 0);
        s[ntl] = __builtin_amdgcn_mfma_f32_16x16x32_bf16(kc1, qf[1], s[ntl], 0, 0, 0);
      }
      __builtin_amdgcn_s_setprio(0);

      // ---- bias + 2^x + pack ----
      unsigned W0[8], W1[8];
      #pragma unroll
      for (int ntl = 0; ntl < 8; ntl++){
        float bh = rsh[8 * a + KH8[tb][ntl]];
        float4 w = wreg[J8[tb][ntl]];
        float p0 = fast_exp2(s[ntl][0] + bh + w.x);
        float p1 = fast_exp2(s[ntl][1] + bh + w.y);
        float p2 = fast_exp2(s[ntl][2] + bh + w.z);
        float p3 = fast_exp2(s[ntl][3] + bh + w.w);
        lrun += (p0 + p1) + (p2 + p3);
        asm("v_cvt_pk_bf16_f32 %0, %1, %2" : "=v"(W0[ntl]) : "v"(p0), "v"(p1));
        asm("v_cvt_pk_bf16_f32 %0, %1, %2" : "=v"(W1[ntl]) : "v"(p2), "v"(p3));
      }

      // ---- in-register P redistribution: pf[ks] elem j = key 32ks+8g+j ----
      bf16x8 pf[4];
      #pragma unroll
      for (int ks = 0; ks < 4; ks++){
        unsigned a0 = (unsigned)__shfl((int)W0[2*ks],   srcA);
        unsigned a1 = (unsigned)__shfl((int)W0[2*ks+1], srcA);
        unsigned b0 = (unsigned)__shfl((int)W1[2*ks],   srcA);
        unsigned b1 = (unsigned)__shfl((int)W1[2*ks+1], srcA);
        unsigned c0 = (unsigned)__shfl((int)W0[2*ks],   srcB);
        unsigned c1 = (unsigned)__shfl((int)W0[2*ks+1], srcB);
        unsigned d0 = (unsigned)__shfl((int)W1[2*ks],   srcB);
        unsigned d1 = (unsigned)__shfl((int)W1[2*ks+1], srcB);
        union { unsigned w[4]; bf16x8 v; } u;
        u.w[0] = hi ? a1 : a0;
        u.w[1] = hi ? b1 : b0;
        u.w[2] = hi ? c1 : c0;
        u.w[3] = hi ? d1 : d0;
        pf[ks] = u.v;
      }

      // ---- PV ----
      __builtin_amdgcn_s_setprio(1);
      #pragma unroll
      for (int dt = 0; dt < 4; dt++){
        #pragma unroll
        for (int ks = 0; ks < 4; ks++){
          bf16x8 vf = *(const bf16x8*)&VsB[(dt * 16 + r) * 128 + (((ks * 4 + g) ^ (r & 7)) << 3)];
          Oa[dt] = __builtin_amdgcn_mfma_f32_16x16x32_bf16(pf[ks], vf, Oa[dt], 0, 0, 0);
        }
      }
      __builtin_amdgcn_s_setprio(0);

      __syncthreads();   // drains stage loads + protects buf swap
      buf ^= 1;
    }
  }
#undef STAGE_TILE

  // ---- epilogue ----
  {
    float l = lrun;
    l += __shfl_xor(l, 16);
    l += __shfl_xor(l, 32);
    if (lane < 16) lsh[wv * 16 + lane] = l;
  }
  __syncthreads();
  float invL[4];
  #pragma unroll
  for (int reg = 0; reg < 4; reg++) invL[reg] = 1.f / lsh[wv * 16 + g * 4 + reg];
  #pragma unroll
  for (int dt = 0; dt < 4; dt++)
    #pragma unroll
    for (int reg = 0; reg < 4; reg++){
      int token = q0 + wv * 16 + g * 4 + reg;
      ao[(size_t)token * 768 + head * 64 + dt * 16 + r] = f2bf(Oa[dt][reg] * invL[reg]);
    }
}

// ---------------- proj GEMM ----------------
__global__ __launch_bounds__(256) void proj_gemm(
    const unsigned short* __restrict__ ag,   // [2304][768] bf16
    const unsigned short* __restrict__ wg,   // [768][768] bf16
    const float* __restrict__ bias,
    float* __restrict__ out)
{
  __shared__ short As[64*64];
  __shared__ short Bs[64*64];
  const int tid = threadIdx.x;
  const int lane = tid & 63;
  const int wv = tid >> 6;
  const int r = lane & 15, g = lane >> 4;
  const int wm = (wv >> 1) * 32, wn = (wv & 1) * 32;
  const int m0 = blockIdx.y * 64, n0 = blockIdx.x * 64;

  f32x4 acc[2][2];
  #pragma unroll
  for (int i = 0; i < 2; i++)
    #pragma unroll
    for (int j = 0; j < 2; j++) acc[i][j] = (f32x4){0.f, 0.f, 0.f, 0.f};

  for (int k0 = 0; k0 < 768; k0 += 64){
    __syncthreads();
    #pragma unroll
    for (int it = 0; it < 2; it++){
      int f = it * 256 + tid;
      int row = f >> 3, u = f & 7;
      int us = ((u ^ (row & 7)) << 3);
      gload_lds16(ag + (size_t)(m0 + row) * 768 + k0 + us, &As[f * 8]);
      gload_lds16(wg + (size_t)(n0 + row) * 768 + k0 + us, &Bs[f * 8]);
    }
    __syncthreads();
    #pragma unroll
    for (int ks = 0; ks < 2; ks++){
      bf16x8 af[2], bfr[2];
      #pragma unroll
      for (int mt = 0; mt < 2; mt++){
        int row = wm + mt * 16 + r;
        af[mt] = *(const bf16x8*)&As[row * 64 + ((((ks << 2) | g) ^ (r & 7)) << 3)];
      }
      #pragma unroll
      for (int nt = 0; nt < 2; nt++){
        int row = wn + nt * 16 + r;
        bfr[nt] = *(const bf16x8*)&Bs[row * 64 + ((((ks << 2) | g) ^ (r & 7)) << 3)];
      }
      #pragma unroll
      for (int mt = 0; mt < 2; mt++)
        #pragma unroll
        for (int nt = 0; nt < 2; nt++)
          acc[mt][nt] = __builtin_amdgcn_mfma_f32_16x16x32_bf16(af[mt], bfr[nt], acc[mt][nt], 0, 0, 0);
    }
  }

  #pragma unroll
  for (int mt = 0; mt < 2; mt++)
    #pragma unroll
    for (int reg = 0; reg < 4; reg++){
      int row_m = m0 + wm + mt * 16 + g * 4 + reg;
      #pragma unroll
      for (int nt = 0; nt < 2; nt++){
        int col = n0 + wn + nt * 16 + r;
        out[(size_t)row_m * 768 + col] = acc[mt][nt][reg] + bias[col];
      }
    }
}

extern "C" void kernel_launch(void* const* d_in, const int* in_sizes, int n_in,
                              void* d_out, int out_size, void* d_ws, size_t ws_size,
                              hipStream_t stream){
  (void)in_sizes; (void)n_in; (void)out_size; (void)ws_size;
  const float* x      = (const float*)d_in[0];
  const float* qkv_w  = (const float*)d_in[1];
  const float* qkv_b  = (const float*)d_in[2];
  const float* proj_w = (const float*)d_in[3];
  const float* proj_b = (const float*)d_in[4];
  const float* rph    = (const float*)d_in[5];
  const float* rpw    = (const float*)d_in[6];
  const float* Aq     = (const float*)d_in[7];
  const float* Bq     = (const float*)d_in[8];
  const float* Ak     = (const float*)d_in[9];
  const float* Bk     = (const float*)d_in[10];
  const float* Av     = (const float*)d_in[11];
  const float* Bv     = (const float*)d_in[12];

  char* w = (char*)d_ws;
  unsigned short* xb  = (unsigned short*)(w + 0);         // 2304*768 bf16
  unsigned short* wqb = (unsigned short*)(w + 3538944);   // 2304*768 bf16
  unsigned short* wpb = (unsigned short*)(w + 7077888);   //  768*768 bf16
  unsigned short* qb  = (unsigned short*)(w + 8257536);   // 12*2304*64 bf16 (scaled)
  unsigned short* kb  = (unsigned short*)(w + 11796480);  // 12*2304*64 bf16
  unsigned short* vtb = (unsigned short*)(w + 15335424);  // 12*64*2304 bf16
  float* tb           = (float*)(w + 18874368);           // 3*2304*4 f32
  float* rhb          = (float*)(w + 18984960);           // 12*2304*48 f32
  float* rwb          = (float*)(w + 24293376);           // 12*2304*48 f32
  unsigned short* aob = (unsigned short*)(w + 29601792);  // 2304*768 bf16

  cvt_all<<<4032, 256, 0, stream>>>(x, qkv_w, proj_w, xb, wqb, wpb);
  lora_t_kernel<<<576, 256, 0, stream>>>(x, Aq, Ak, Av, tb);
  qkv_gemm<<<dim3(36, 18), 256, 0, stream>>>(xb, wqb, qkv_b, tb, Bq, Bk, Bv, qb, kb, vtb);
  rel_gemm<<<dim3(48, 12), 256, 0, stream>>>(qb, rph, rpw, rhb, rwb);
  attn_kernel<<<dim3(36, 12), 256, 0, stream>>>(qb, kb, vtb, rhb, rwb, aob);
  proj_gemm<<<dim3(12, 36), 256, 0, stream>>>(aob, wpb, proj_b, (float*)d_out);
}

// Round 19
// 109.441 us; speedup vs baseline: 1.0102x; 1.0102x over previous
//
#include <hip/hip_runtime.h>

#define NTOK 2304   // 48*48 tokens
#define NH 12
#define HD 64

typedef __attribute__((ext_vector_type(8))) short bf16x8;
typedef __attribute__((ext_vector_type(4))) float f32x4;

__device__ __forceinline__ unsigned short f2bf(float f){
  union { float f; unsigned u; } v; v.f = f;
  unsigned r = v.u + 0x7fffu + ((v.u >> 16) & 1u);
  return (unsigned short)(r >> 16);
}
__device__ __forceinline__ float bf2f(unsigned short h){
  union { unsigned u; float f; } v; v.u = ((unsigned)h) << 16;
  return v.f;
}
__device__ __forceinline__ float fast_exp2(float x){
  float r;
  asm("v_exp_f32 %0, %1" : "=v"(r) : "v"(x));   // D = 2^S0, single trans op
  return r;
}
__device__ __forceinline__ void gload_lds16(const void* g, void* lds){
  __builtin_amdgcn_global_load_lds(
    (const __attribute__((address_space(1))) unsigned int*)g,
    (__attribute__((address_space(3))) unsigned int*)lds, 16, 0, 0);
}

// ---------------- fp32 -> bf16 convert (x, qkv_w, proj_w) ----------------
__global__ __launch_bounds__(256) void cvt_all(
    const float* __restrict__ x, const float* __restrict__ qw, const float* __restrict__ pw,
    unsigned short* __restrict__ xb, unsigned short* __restrict__ wqb, unsigned short* __restrict__ wpb){
  int i = blockIdx.x * 256 + threadIdx.x;   // 1032192 float4 units total
  const float* src; unsigned short* dst; int off;
  if (i < 442368)      { src = x;  dst = xb;  off = i; }
  else if (i < 884736) { src = qw; dst = wqb; off = i - 442368; }
  else                 { src = pw; dst = wpb; off = i - 884736; }
  float4 v = ((const float4*)src)[off];
  union { unsigned short u[4]; unsigned long long ll; } o;
  o.u[0] = f2bf(v.x); o.u[1] = f2bf(v.y); o.u[2] = f2bf(v.z); o.u[3] = f2bf(v.w);
  ((unsigned long long*)dst)[off] = o.ll;
}

// ---------------- LoRA t = x @ A^T  (t[3][2304][4]) ----------------
__global__ __launch_bounds__(256) void lora_t_kernel(const float* __restrict__ x,
    const float* __restrict__ Aq, const float* __restrict__ Ak, const float* __restrict__ Av,
    float* __restrict__ t){
  int wave = (blockIdx.x * 256 + threadIdx.x) >> 6;   // token
  int lane = threadIdx.x & 63;
  if (wave >= NTOK) return;
  const float* xr = x + (size_t)wave * 768;
  float part[12];
  #pragma unroll
  for (int j = 0; j < 12; j++) part[j] = 0.f;
  for (int k = lane; k < 768; k += 64){
    float xv = xr[k];
    #pragma unroll
    for (int r = 0; r < 4; r++){
      part[r]     += xv * Aq[r*768 + k];
      part[4 + r] += xv * Ak[r*768 + k];
      part[8 + r] += xv * Av[r*768 + k];
    }
  }
  #pragma unroll
  for (int j = 0; j < 12; j++){
    float v = part[j];
    #pragma unroll
    for (int off = 32; off; off >>= 1) v += __shfl_xor(v, off);
    if (lane == 0){
      int mat = j >> 2, r = j & 3;
      t[((size_t)mat * NTOK + wave) * 4 + r] = v;
    }
  }
}

// ---------------- fused qkv GEMM (+bias +LoRA, writes q(scaled),k,vT) ----------------
// q pre-scale = 0.125*log2(e): MFMA emits S*log2e; rel_gemm's G*8 then emits
// rel*log2e automatically -> attn uses raw v_exp_f32 (2^x) with no multiplies.
__global__ __launch_bounds__(256) void qkv_gemm(
    const unsigned short* __restrict__ xg,   // [2304][768] bf16
    const unsigned short* __restrict__ wg,   // [2304][768] bf16
    const float* __restrict__ bias,          // [2304]
    const float* __restrict__ t,             // [3][2304][4]
    const float* __restrict__ Bq, const float* __restrict__ Bk, const float* __restrict__ Bv, // [768][4]
    unsigned short* __restrict__ qo,         // [12][2304][64]  (pre-scaled)
    unsigned short* __restrict__ ko,         // [12][2304][64]
    unsigned short* __restrict__ vT)         // [12][64][2304]
{
  __shared__ short As[128*64];
  __shared__ short Bs[64*64];
  const int tid = threadIdx.x;
  const int lane = tid & 63;
  const int wv = tid >> 6;
  const int r = lane & 15, g = lane >> 4;
  const int wm = (wv >> 1) * 64, wn = (wv & 1) * 32;
  const int m0 = blockIdx.y * 128, n0 = blockIdx.x * 64;

  f32x4 acc[4][2];
  #pragma unroll
  for (int i = 0; i < 4; i++)
    #pragma unroll
    for (int j = 0; j < 2; j++) acc[i][j] = (f32x4){0.f, 0.f, 0.f, 0.f};

  for (int k0 = 0; k0 < 768; k0 += 64){
    __syncthreads();
    #pragma unroll
    for (int it = 0; it < 4; it++){
      int f = it * 256 + tid;
      int row = f >> 3, u = f & 7;
      int us = ((u ^ (row & 7)) << 3);
      gload_lds16(xg + (size_t)(m0 + row) * 768 + k0 + us, &As[f * 8]);
    }
    #pragma unroll
    for (int it = 0; it < 2; it++){
      int f = it * 256 + tid;
      int row = f >> 3, u = f & 7;
      int us = ((u ^ (row & 7)) << 3);
      gload_lds16(wg + (size_t)(n0 + row) * 768 + k0 + us, &Bs[f * 8]);
    }
    __syncthreads();
    #pragma unroll
    for (int ks = 0; ks < 2; ks++){
      bf16x8 af[4], bfr[2];
      #pragma unroll
      for (int mt = 0; mt < 4; mt++){
        int row = wm + mt * 16 + r;
        af[mt] = *(const bf16x8*)&As[row * 64 + ((((ks << 2) | g) ^ (r & 7)) << 3)];
      }
      #pragma unroll
      for (int nt = 0; nt < 2; nt++){
        int row = wn + nt * 16 + r;
        bfr[nt] = *(const bf16x8*)&Bs[row * 64 + ((((ks << 2) | g) ^ (r & 7)) << 3)];
      }
      #pragma unroll
      for (int mt = 0; mt < 4; mt++)
        #pragma unroll
        for (int nt = 0; nt < 2; nt++)
          acc[mt][nt] = __builtin_amdgcn_mfma_f32_16x16x32_bf16(af[mt], bfr[nt], acc[mt][nt], 0, 0, 0);
    }
  }

  const int part = n0 / 768;   // 64 | 768 -> block never straddles parts
  const float* Bl = (part == 0) ? Bq : ((part == 1) ? Bk : Bv);
  const float* tp = t + (size_t)part * NTOK * 4;
  #pragma unroll
  for (int mt = 0; mt < 4; mt++){
    #pragma unroll
    for (int reg = 0; reg < 4; reg++){
      int row_m = m0 + wm + mt * 16 + g * 4 + reg;
      float4 tv = *(const float4*)&tp[row_m * 4];
      #pragma unroll
      for (int nt = 0; nt < 2; nt++){
        int col = n0 + wn + nt * 16 + r;
        int cc = col - part * 768;
        float4 bw = *(const float4*)&Bl[cc * 4];
        float val = acc[mt][nt][reg] + bias[col]
                  + 0.25f * (tv.x * bw.x + tv.y * bw.y + tv.z * bw.z + tv.w * bw.w);
        int head = cc >> 6, d = cc & 63;
        if (part == 0)      qo[((size_t)head * NTOK + row_m) * 64 + d] = f2bf(val * 0.18033688f);
        else if (part == 1) ko[((size_t)head * NTOK + row_m) * 64 + d] = f2bf(val);
        else                vT[((size_t)head * 64 + d) * NTOK + row_m] = f2bf(val);
      }
    }
  }
}

// ---------------- rel_h / rel_w via MFMA (rel_pos converted in-kernel) ----------------
// q carries 0.125*log2e; G*8 therefore yields rel*log2e (what v_exp_f32 needs).
__global__ __launch_bounds__(256, 2) void rel_gemm(
    const unsigned short* __restrict__ qg,    // [12][2304][64] bf16 (scaled)
    const float* __restrict__ rph,            // [95][64] f32
    const float* __restrict__ rpw,            // [95][64] f32
    float* __restrict__ rel_h,                // [12][2304][48]
    float* __restrict__ rel_w)                // [12][2304][48]
{
  __shared__ float G[48 * 196];
  const int ih = blockIdx.x, head = blockIdx.y;
  const int tid = threadIdx.x, lane = tid & 63, wv = tid >> 6;
  const int r = lane & 15, g = lane >> 4;
  const int q0 = ih * 48;

  bf16x8 af[3][2];
  #pragma unroll
  for (int mt = 0; mt < 3; mt++)
    #pragma unroll
    for (int ks = 0; ks < 2; ks++)
      af[mt][ks] = *(const bf16x8*)&qg[((size_t)head * NTOK + q0 + mt * 16 + r) * 64 + ks * 32 + g * 8];

  bf16x8 bfv[3][2];
  #pragma unroll
  for (int nt = 0; nt < 3; nt++){
    int col = wv * 48 + nt * 16 + r;
    const float* src = (col < 95) ? &rph[(size_t)col * 64]
                     : (col < 190) ? &rpw[(size_t)(col - 95) * 64]
                     : &rpw[0];
    #pragma unroll
    for (int ks = 0; ks < 2; ks++){
      float4 lo = *(const float4*)&src[ks * 32 + g * 8];
      float4 hi = *(const float4*)&src[ks * 32 + g * 8 + 4];
      union { unsigned short u[8]; bf16x8 v; } t;
      t.u[0] = f2bf(lo.x); t.u[1] = f2bf(lo.y); t.u[2] = f2bf(lo.z); t.u[3] = f2bf(lo.w);
      t.u[4] = f2bf(hi.x); t.u[5] = f2bf(hi.y); t.u[6] = f2bf(hi.z); t.u[7] = f2bf(hi.w);
      bfv[nt][ks] = t.v;
    }
  }

  f32x4 acc[3][3];
  #pragma unroll
  for (int mt = 0; mt < 3; mt++)
    #pragma unroll
    for (int nt = 0; nt < 3; nt++) acc[mt][nt] = (f32x4){0.f, 0.f, 0.f, 0.f};
  #pragma unroll
  for (int ks = 0; ks < 2; ks++)
    #pragma unroll
    for (int mt = 0; mt < 3; mt++)
      #pragma unroll
      for (int nt = 0; nt < 3; nt++)
        acc[mt][nt] = __builtin_amdgcn_mfma_f32_16x16x32_bf16(af[mt][ks], bfv[nt][ks], acc[mt][nt], 0, 0, 0);

  #pragma unroll
  for (int mt = 0; mt < 3; mt++)
    #pragma unroll
    for (int reg = 0; reg < 4; reg++){
      int row = mt * 16 + g * 4 + reg;
      #pragma unroll
      for (int nt = 0; nt < 3; nt++)
        G[row * 196 + wv * 48 + nt * 16 + r] = acc[mt][nt][reg];
    }
  __syncthreads();

  for (int idx = tid; idx < 48 * 96; idx += 256){
    int i = idx / 96, c = idx % 96;
    size_t gi = (size_t)head * NTOK + q0 + i;
    if (c < 48) rel_h[gi * 48 + c]        = G[i * 196 + (ih + 47 - c)] * 8.f;
    else        rel_w[gi * 48 + (c - 48)] = G[i * 196 + 95 + (i + 47 - (c - 48))] * 8.f;
  }
}

// ---------------- flash attention (R12-exact structure; raw v_exp_f32) ----------------
__global__ __launch_bounds__(256, 3) void attn_kernel(
    const unsigned short* __restrict__ qg,   // [12][2304][64] scaled (log2e absorbed)
    const unsigned short* __restrict__ kg,   // [12][2304][64]
    const unsigned short* __restrict__ vT,   // [12][64][2304]
    const float* __restrict__ rel_h,         // [12][2304][48] (*log2e)
    const float* __restrict__ rel_w,         // [12][2304][48] (*log2e)
    unsigned short* __restrict__ ao)         // [2304][768]
{
  // Ks[2][64][64]us @0 | Vs[2][64][64]us @16384 | relH[64][52]f32 @32768 | lsh @46080
  __shared__ __align__(16) char smem[46336];
  unsigned short* Ks = (unsigned short*)smem;
  unsigned short* Vs = (unsigned short*)(smem + 16384);
  float* relH = (float*)(smem + 32768);
  float* lsh = (float*)(smem + 46080);

  const int head = blockIdx.y;
  const int q0 = blockIdx.x * 64;
  const int tid = threadIdx.x, lane = tid & 63, wv = tid >> 6;
  const int r = lane & 15, g = lane >> 4;

  const unsigned short* kbase = kg + (size_t)head * NTOK * 64;
  const unsigned short* vbase = vT + (size_t)head * 64 * NTOK;

  // rel_h stage (f32, stride 52 -> 16B-aligned rows, float4)
  for (int idx = tid; idx < 64 * 12; idx += 256){
    int i = idx / 12, c4 = idx % 12;
    *(float4*)&relH[i * 52 + c4 * 4] =
        *(const float4*)&rel_h[((size_t)head * NTOK + q0 + i) * 48 + c4 * 4];
  }

  // rel_w: 3 static float4s per lane (row = wv*16+r, cols 16j+4g..+3), full f32
  float4 wreg[3];
  #pragma unroll
  for (int j = 0; j < 3; j++)
    wreg[j] = *(const float4*)&rel_w[((size_t)head * NTOK + q0 + wv * 16 + r) * 48 + j * 16 + g * 4];

  bf16x8 qf[2];
  #pragma unroll
  for (int ks = 0; ks < 2; ks++)
    qf[ks] = *(const bf16x8*)&qg[((size_t)head * NTOK + q0 + wv * 16 + r) * 64 + ks * 32 + g * 8];

  const int rowIn = lane >> 3, uu = lane & 7;

  // prologue: stage tile 0 into buf 0
  #pragma unroll
  for (int s2 = 0; s2 < 2; s2++){
    int seg = wv * 2 + s2;
    int row = seg * 8 + rowIn;
    gload_lds16(kbase + (size_t)row * 64 + ((uu ^ (row & 7)) << 3), &Ks[seg * 512 + lane * 8]);
    gload_lds16(vbase + (size_t)row * NTOK + ((uu ^ (row & 7)) << 3), &Vs[seg * 512 + lane * 8]);
  }
  __syncthreads();

  f32x4 Oa[4];
  float lrun = 0.f;
  #pragma unroll
  for (int dt = 0; dt < 4; dt++) Oa[dt] = (f32x4){0.f, 0.f, 0.f, 0.f};

  const float* rsh = &relH[(wv * 16 + r) * 52];

  // e = 4t+ntl, t = 3a+tb -> kh = 4a + KH[tb][ntl], j = J[tb][ntl]
  const int KH_T[3][4] = {{0,0,0,1},{1,1,2,2},{2,3,3,3}};
  const int J_T[3][4]  = {{0,1,2,0},{1,2,0,1},{2,0,1,2}};

  const int srcA = r + ((g & 1) << 5);   // lane (r, 2*(g&1))
  const int srcB = srcA + 16;            // lane (r, 2*(g&1)+1)
  const int hi = (g >> 1);

  int buf = 0;
  for (int a = 0; a < 12; a++){
    #pragma unroll
    for (int tb = 0; tb < 3; tb++){
      const int t = a * 3 + tb;
      unsigned short* KsB = &Ks[buf * 4096];
      unsigned short* VsB = &Vs[buf * 4096];

      if (t < 35){
        const int key0n = (t + 1) * 64;
        unsigned short* KsN = &Ks[(buf ^ 1) * 4096];
        unsigned short* VsN = &Vs[(buf ^ 1) * 4096];
        #pragma unroll
        for (int s2 = 0; s2 < 2; s2++){
          int seg = wv * 2 + s2;
          int row = seg * 8 + rowIn;
          gload_lds16(kbase + (size_t)(key0n + row) * 64 + ((uu ^ (row & 7)) << 3),
                      &KsN[seg * 512 + lane * 8]);
          gload_lds16(vbase + (size_t)row * NTOK + key0n + ((uu ^ (row & 7)) << 3),
                      &VsN[seg * 512 + lane * 8]);
        }
      }

      // ---- QK^T (swapped): s[ntl] = S[key=16ntl+4g+reg][q=r]  (carries log2e) ----
      f32x4 s[4];
      __builtin_amdgcn_s_setprio(1);
      #pragma unroll
      for (int ntl = 0; ntl < 4; ntl++){
        bf16x8 kc0 = *(const bf16x8*)&KsB[(ntl * 16 + r) * 64 + ((g ^ (r & 7)) << 3)];
        bf16x8 kc1 = *(const bf16x8*)&KsB[(ntl * 16 + r) * 64 + (((4 + g) ^ (r & 7)) << 3)];
        s[ntl] = (f32x4){0.f, 0.f, 0.f, 0.f};
        s[ntl] = __builtin_amdgcn_mfma_f32_16x16x32_bf16(kc0, qf[0], s[ntl], 0, 0, 0);
        s[ntl] = __builtin_amdgcn_mfma_f32_16x16x32_bf16(kc1, qf[1], s[ntl], 0, 0, 0);
      }
      __builtin_amdgcn_s_setprio(0);

      // ---- bias + 2^x + pack (W0/W1 per ntl) ----
      unsigned W0[4], W1[4];
      #pragma unroll
      for (int ntl = 0; ntl < 4; ntl++){
        float bh = rsh[4 * a + KH_T[tb][ntl]];
        float4 w = wreg[J_T[tb][ntl]];
        float p0 = fast_exp2(s[ntl][0] + bh + w.x);
        float p1 = fast_exp2(s[ntl][1] + bh + w.y);
        float p2 = fast_exp2(s[ntl][2] + bh + w.z);
        float p3 = fast_exp2(s[ntl][3] + bh + w.w);
        lrun += (p0 + p1) + (p2 + p3);
        asm("v_cvt_pk_bf16_f32 %0, %1, %2" : "=v"(W0[ntl]) : "v"(p0), "v"(p1));
        asm("v_cvt_pk_bf16_f32 %0, %1, %2" : "=v"(W1[ntl]) : "v"(p2), "v"(p3));
      }

      // ---- in-register P redistribution: pf[ks] elem j = key 32ks+8g+j ----
      bf16x8 pf[2];
      #pragma unroll
      for (int ks = 0; ks < 2; ks++){
        unsigned a0 = (unsigned)__shfl((int)W0[2*ks],   srcA);
        unsigned a1 = (unsigned)__shfl((int)W0[2*ks+1], srcA);
        unsigned b0 = (unsigned)__shfl((int)W1[2*ks],   srcA);
        unsigned b1 = (unsigned)__shfl((int)W1[2*ks+1], srcA);
        unsigned c0 = (unsigned)__shfl((int)W0[2*ks],   srcB);
        unsigned c1 = (unsigned)__shfl((int)W0[2*ks+1], srcB);
        unsigned d0 = (unsigned)__shfl((int)W1[2*ks],   srcB);
        unsigned d1 = (unsigned)__shfl((int)W1[2*ks+1], srcB);
        union { unsigned w[4]; bf16x8 v; } u;
        u.w[0] = hi ? a1 : a0;
        u.w[1] = hi ? b1 : b0;
        u.w[2] = hi ? c1 : c0;
        u.w[3] = hi ? d1 : d0;
        pf[ks] = u.v;
      }

      // ---- PV ----
      __builtin_amdgcn_s_setprio(1);
      #pragma unroll
      for (int dt = 0; dt < 4; dt++){
        #pragma unroll
        for (int ks = 0; ks < 2; ks++){
          bf16x8 vf = *(const bf16x8*)&VsB[(dt * 16 + r) * 64 + (((ks * 4 + g) ^ (r & 7)) << 3)];
          Oa[dt] = __builtin_amdgcn_mfma_f32_16x16x32_bf16(pf[ks], vf, Oa[dt], 0, 0, 0);
        }
      }
      __builtin_amdgcn_s_setprio(0);

      __syncthreads();   // drains stage loads + protects buf swap
      buf ^= 1;
    }
  }

  // ---- epilogue ----
  {
    float l = lrun;
    l += __shfl_xor(l, 16);
    l += __shfl_xor(l, 32);
    if (lane < 16) lsh[wv * 16 + lane] = l;
  }
  __syncthreads();
  float invL[4];
  #pragma unroll
  for (int reg = 0; reg < 4; reg++) invL[reg] = 1.f / lsh[wv * 16 + g * 4 + reg];
  #pragma unroll
  for (int dt = 0; dt < 4; dt++)
    #pragma unroll
    for (int reg = 0; reg < 4; reg++){
      int token = q0 + wv * 16 + g * 4 + reg;
      ao[(size_t)token * 768 + head * 64 + dt * 16 + r] = f2bf(Oa[dt][reg] * invL[reg]);
    }
}

// ---------------- proj GEMM ----------------
__global__ __launch_bounds__(256) void proj_gemm(
    const unsigned short* __restrict__ ag,   // [2304][768] bf16
    const unsigned short* __restrict__ wg,   // [768][768] bf16
    const float* __restrict__ bias,
    float* __restrict__ out)
{
  __shared__ short As[64*64];
  __shared__ short Bs[64*64];
  const int tid = threadIdx.x;
  const int lane = tid & 63;
  const int wv = tid >> 6;
  const int r = lane & 15, g = lane >> 4;
  const int wm = (wv >> 1) * 32, wn = (wv & 1) * 32;
  const int m0 = blockIdx.y * 64, n0 = blockIdx.x * 64;

  f32x4 acc[2][2];
  #pragma unroll
  for (int i = 0; i < 2; i++)
    #pragma unroll
    for (int j = 0; j < 2; j++) acc[i][j] = (f32x4){0.f, 0.f, 0.f, 0.f};

  for (int k0 = 0; k0 < 768; k0 += 64){
    __syncthreads();
    #pragma unroll
    for (int it = 0; it < 2; it++){
      int f = it * 256 + tid;
      int row = f >> 3, u = f & 7;
      int us = ((u ^ (row & 7)) << 3);
      gload_lds16(ag + (size_t)(m0 + row) * 768 + k0 + us, &As[f * 8]);
      gload_lds16(wg + (size_t)(n0 + row) * 768 + k0 + us, &Bs[f * 8]);
    }
    __syncthreads();
    #pragma unroll
    for (int ks = 0; ks < 2; ks++){
      bf16x8 af[2], bfr[2];
      #pragma unroll
      for (int mt = 0; mt < 2; mt++){
        int row = wm + mt * 16 + r;
        af[mt] = *(const bf16x8*)&As[row * 64 + ((((ks << 2) | g) ^ (r & 7)) << 3)];
      }
      #pragma unroll
      for (int nt = 0; nt < 2; nt++){
        int row = wn + nt * 16 + r;
        bfr[nt] = *(const bf16x8*)&Bs[row * 64 + ((((ks << 2) | g) ^ (r & 7)) << 3)];
      }
      #pragma unroll
      for (int mt = 0; mt < 2; mt++)
        #pragma unroll
        for (int nt = 0; nt < 2; nt++)
          acc[mt][nt] = __builtin_amdgcn_mfma_f32_16x16x32_bf16(af[mt], bfr[nt], acc[mt][nt], 0, 0, 0);
    }
  }

  #pragma unroll
  for (int mt = 0; mt < 2; mt++)
    #pragma unroll
    for (int reg = 0; reg < 4; reg++){
      int row_m = m0 + wm + mt * 16 + g * 4 + reg;
      #pragma unroll
      for (int nt = 0; nt < 2; nt++){
        int col = n0 + wn + nt * 16 + r;
        out[(size_t)row_m * 768 + col] = acc[mt][nt][reg] + bias[col];
      }
    }
}

extern "C" void kernel_launch(void* const* d_in, const int* in_sizes, int n_in,
                              void* d_out, int out_size, void* d_ws, size_t ws_size,
                              hipStream_t stream){
  (void)in_sizes; (void)n_in; (void)out_size; (void)ws_size;
  const float* x      = (const float*)d_in[0];
  const float* qkv_w  = (const float*)d_in[1];
  const float* qkv_b  = (const float*)d_in[2];
  const float* proj_w = (const float*)d_in[3];
  const float* proj_b = (const float*)d_in[4];
  const float* rph    = (const float*)d_in[5];
  const float* rpw    = (const float*)d_in[6];
  const float* Aq     = (const float*)d_in[7];
  const float* Bq     = (const float*)d_in[8];
  const float* Ak     = (const float*)d_in[9];
  const float* Bk     = (const float*)d_in[10];
  const float* Av     = (const float*)d_in[11];
  const float* Bv     = (const float*)d_in[12];

  char* w = (char*)d_ws;
  unsigned short* xb  = (unsigned short*)(w + 0);         // 2304*768 bf16
  unsigned short* wqb = (unsigned short*)(w + 3538944);   // 2304*768 bf16
  unsigned short* wpb = (unsigned short*)(w + 7077888);   //  768*768 bf16
  unsigned short* qb  = (unsigned short*)(w + 8257536);   // 12*2304*64 bf16 (scaled)
  unsigned short* kb  = (unsigned short*)(w + 11796480);  // 12*2304*64 bf16
  unsigned short* vtb = (unsigned short*)(w + 15335424);  // 12*64*2304 bf16
  float* tb           = (float*)(w + 18874368);           // 3*2304*4 f32
  float* rhb          = (float*)(w + 18984960);           // 12*2304*48 f32
  float* rwb          = (float*)(w + 24293376);           // 12*2304*48 f32
  unsigned short* aob = (unsigned short*)(w + 29601792);  // 2304*768 bf16

  cvt_all<<<4032, 256, 0, stream>>>(x, qkv_w, proj_w, xb, wqb, wpb);
  lora_t_kernel<<<576, 256, 0, stream>>>(x, Aq, Ak, Av, tb);
  qkv_gemm<<<dim3(36, 18), 256, 0, stream>>>(xb, wqb, qkv_b, tb, Bq, Bk, Bv, qb, kb, vtb);
  rel_gemm<<<dim3(48, 12), 256, 0, stream>>>(qb, rph, rpw, rhb, rwb);
  attn_kernel<<<dim3(36, 12), 256, 0, stream>>>(qb, kb, vtb, rhb, rwb, aob);
  proj_gemm<<<dim3(12, 36), 256, 0, stream>>>(aob, wpb, proj_b, (float*)d_out);
}